// Round 1
// baseline (127.676 us; speedup 1.0000x reference)
//
#include <hip/hip_runtime.h>

// SoftErosion3D, connectivity=6, iterations=2, shape [2,1,256,256,256] f32.
// Each iteration: out = im^2 * prod(6 face neighbors), pad=1.0.
// Two passes: d_in -> d_ws -> d_out. Memory-bound 7-point stencil.

#define BB 2
#define DD 256
#define HH 256
#define WW 256
#define HWQ (HH * WW)           // 65536
#define WV  (WW / 4)            // 64 float4 per row
#define NVEC (BB * DD * HH * WV) // 8,388,608

__global__ __launch_bounds__(256) void erode6_pass(const float* __restrict__ in,
                                                   float* __restrict__ out) {
    int tid = blockIdx.x * blockDim.x + threadIdx.x;
    if (tid >= NVEC) return;

    // layout is fully contiguous: base element index = tid*4
    int wv = tid & (WV - 1);
    int h  = (tid >> 6)  & (HH - 1);
    int d  = (tid >> 14) & (DD - 1);
    int base = tid << 2;

    float4 c = *reinterpret_cast<const float4*>(in + base);

    // center^2 (offset set includes the center, and out = im * prod)
    float4 r;
    r.x = c.x * c.x;
    r.y = c.y * c.y;
    r.z = c.z * c.z;
    r.w = c.w * c.w;

    // W-direction neighbors: mostly in-register, 2 scalar edge loads
    float lw = (wv > 0)      ? in[base - 1] : 1.0f;
    float rw = (wv < WV - 1) ? in[base + 4] : 1.0f;
    r.x *= lw  * c.y;
    r.y *= c.x * c.z;
    r.z *= c.y * c.w;
    r.w *= c.z * rw;

    // H-direction neighbors
    if (h > 0) {
        float4 n = *reinterpret_cast<const float4*>(in + base - WW);
        r.x *= n.x; r.y *= n.y; r.z *= n.z; r.w *= n.w;
    }
    if (h < HH - 1) {
        float4 n = *reinterpret_cast<const float4*>(in + base + WW);
        r.x *= n.x; r.y *= n.y; r.z *= n.z; r.w *= n.w;
    }

    // D-direction neighbors (d is within-batch, so guards also handle batch edges)
    if (d > 0) {
        float4 n = *reinterpret_cast<const float4*>(in + base - HWQ);
        r.x *= n.x; r.y *= n.y; r.z *= n.z; r.w *= n.w;
    }
    if (d < DD - 1) {
        float4 n = *reinterpret_cast<const float4*>(in + base + HWQ);
        r.x *= n.x; r.y *= n.y; r.z *= n.z; r.w *= n.w;
    }

    *reinterpret_cast<float4*>(out + base) = r;
}

extern "C" void kernel_launch(void* const* d_in, const int* in_sizes, int n_in,
                              void* d_out, int out_size, void* d_ws, size_t ws_size,
                              hipStream_t stream) {
    const float* in  = (const float*)d_in[0];
    float*       out = (float*)d_out;
    float*       ws  = (float*)d_ws;   // needs 2*256^3*4 = 128 MiB

    dim3 block(256);
    dim3 grid((NVEC + 255) / 256);

    // iteration 1: in -> ws ; iteration 2: ws -> out
    erode6_pass<<<grid, block, 0, stream>>>(in, ws);
    erode6_pass<<<grid, block, 0, stream>>>(ws, out);
}